// Round 1
// baseline (179.186 us; speedup 1.0000x reference)
//
#include <hip/hip_runtime.h>
#include <hip/hip_bf16.h>
#include <math.h>

#define SCALE 0.125f
#define SEQ   1024
#define DH    64
#define QBLK  64
#define KBLK  64
#define LDP   72   // padded LDS row stride (bf16 elems): 144 B, 16B-aligned

typedef short bf16x8 __attribute__((ext_vector_type(8)));
typedef float f32x4  __attribute__((ext_vector_type(4)));

__device__ inline unsigned short f2bf(float f) {
    union { float f; unsigned u; } x; x.f = f;
    unsigned u = x.u;
    u += 0x7FFFu + ((u >> 16) & 1u);   // RNE; inputs are finite normals
    return (unsigned short)(u >> 16);
}

__global__ __launch_bounds__(256)
void attn_fwd(const float* __restrict__ Q, const float* __restrict__ K,
              const float* __restrict__ V, float* __restrict__ O) {
    __shared__ unsigned short Ksh[KBLK][LDP];      // [kk][d]
    __shared__ unsigned short Vsh[DH][LDP];        // transposed: [d][kk]
    __shared__ unsigned short Psh[4][16][LDP];     // per-wave P tile [q][kk]

    const int qt   = blockIdx.x;    // 0..15
    const int bh   = blockIdx.y;    // 0..127
    const int tid  = threadIdx.x;
    const int wave = tid >> 6;
    const int lane = tid & 63;
    const int lhi  = lane >> 4;     // 0..3
    const int llo  = lane & 15;     // 0..15

    const float* Qb = Q + ((size_t)bh * SEQ + qt * QBLK) * DH;
    const float* Kb = K + (size_t)bh * SEQ * DH;
    const float* Vb = V + (size_t)bh * SEQ * DH;
    float*       Ob = O + ((size_t)bh * SEQ + qt * QBLK) * DH;

    // ---- Q fragments (A-operand, rows = wave*16 + llo, k = lhi*8+i + s*32) ----
    bf16x8 qf[2];
    {
        const int qrow = wave * 16 + llo;
        #pragma unroll
        for (int s = 0; s < 2; ++s) {
            const float* p = Qb + qrow * DH + s * 32 + lhi * 8;
            float4 f0 = *(const float4*)(p);
            float4 f1 = *(const float4*)(p + 4);
            qf[s][0] = (short)f2bf(f0.x); qf[s][1] = (short)f2bf(f0.y);
            qf[s][2] = (short)f2bf(f0.z); qf[s][3] = (short)f2bf(f0.w);
            qf[s][4] = (short)f2bf(f1.x); qf[s][5] = (short)f2bf(f1.y);
            qf[s][6] = (short)f2bf(f1.z); qf[s][7] = (short)f2bf(f1.w);
        }
    }

    f32x4 acc[4] = {};              // output accum: acc[dt][r], C-layout
    float m_run[4], l_run[4];
    #pragma unroll
    for (int r = 0; r < 4; ++r) { m_run[r] = -INFINITY; l_run[r] = 0.0f; }

    for (int kt = 0; kt < SEQ / KBLK; ++kt) {
        __syncthreads();            // previous iter's LDS reads done
        // ---- stage K (row-major) and V (transposed) fp32 -> bf16 ----
        {
            const float* Kt = Kb + (size_t)kt * KBLK * DH;
            const float* Vt = Vb + (size_t)kt * KBLK * DH;
            #pragma unroll
            for (int it = 0; it < 4; ++it) {
                const int f  = (it * 256 + tid) * 4;   // float idx in 64x64 tile
                const int kk = f >> 6;
                const int d  = f & 63;
                float4 kv = *(const float4*)(Kt + f);
                union { unsigned short s[4]; uint2 u; } pk;
                pk.s[0] = f2bf(kv.x); pk.s[1] = f2bf(kv.y);
                pk.s[2] = f2bf(kv.z); pk.s[3] = f2bf(kv.w);
                *(uint2*)&Ksh[kk][d] = pk.u;           // 8B aligned
                float4 vv = *(const float4*)(Vt + f);
                Vsh[d + 0][kk] = f2bf(vv.x);
                Vsh[d + 1][kk] = f2bf(vv.y);
                Vsh[d + 2][kk] = f2bf(vv.z);
                Vsh[d + 3][kk] = f2bf(vv.w);
            }
        }
        __syncthreads();

        // ---- QK^T: S[q][kk] = sum_d Q[q][d] K[kk][d] ----
        f32x4 sc[4] = {};           // sc[t16][r]: col = t16*16+llo, row = lhi*4+r
        #pragma unroll
        for (int t = 0; t < 4; ++t) {
            #pragma unroll
            for (int s = 0; s < 2; ++s) {
                bf16x8 b = *(const bf16x8*)&Ksh[t * 16 + llo][s * 32 + lhi * 8];
                sc[t] = __builtin_amdgcn_mfma_f32_16x16x32_bf16(qf[s], b, sc[t], 0, 0, 0);
            }
        }
        #pragma unroll
        for (int t = 0; t < 4; ++t)
            #pragma unroll
            for (int r = 0; r < 4; ++r) sc[t][r] *= SCALE;

        // ---- online softmax (rows owned per lane: lhi*4+r) ----
        float corr[4];
        #pragma unroll
        for (int r = 0; r < 4; ++r) {
            float v = fmaxf(fmaxf(sc[0][r], sc[1][r]), fmaxf(sc[2][r], sc[3][r]));
            v = fmaxf(v, __shfl_xor(v, 1));
            v = fmaxf(v, __shfl_xor(v, 2));
            v = fmaxf(v, __shfl_xor(v, 4));
            v = fmaxf(v, __shfl_xor(v, 8));
            float mn = fmaxf(m_run[r], v);
            corr[r] = __expf(m_run[r] - mn);   // exp(-inf)=0 on first tile
            m_run[r] = mn;
        }
        float rsum[4] = {0.f, 0.f, 0.f, 0.f};
        #pragma unroll
        for (int t = 0; t < 4; ++t) {
            #pragma unroll
            for (int r = 0; r < 4; ++r) {
                float p = __expf(sc[t][r] - m_run[r]);
                rsum[r] += p;
                Psh[wave][lhi * 4 + r][t * 16 + llo] = f2bf(p);
            }
        }
        #pragma unroll
        for (int r = 0; r < 4; ++r) {
            float v = rsum[r];
            v += __shfl_xor(v, 1);
            v += __shfl_xor(v, 2);
            v += __shfl_xor(v, 4);
            v += __shfl_xor(v, 8);
            l_run[r] = l_run[r] * corr[r] + v;
        }
        #pragma unroll
        for (int dt = 0; dt < 4; ++dt)
            #pragma unroll
            for (int r = 0; r < 4; ++r) acc[dt][r] *= corr[r];

        // ---- PV: acc[q][d] += sum_kk P[q][kk] V[kk][d] ----
        #pragma unroll
        for (int s2 = 0; s2 < 2; ++s2) {
            bf16x8 a = *(const bf16x8*)&Psh[wave][llo][s2 * 32 + lhi * 8];
            #pragma unroll
            for (int dt = 0; dt < 4; ++dt) {
                bf16x8 b = *(const bf16x8*)&Vsh[dt * 16 + llo][s2 * 32 + lhi * 8];
                acc[dt] = __builtin_amdgcn_mfma_f32_16x16x32_bf16(a, b, acc[dt], 0, 0, 0);
            }
        }
    }

    // ---- epilogue: O = acc / l ----
    #pragma unroll
    for (int dt = 0; dt < 4; ++dt) {
        #pragma unroll
        for (int r = 0; r < 4; ++r) {
            const int row = wave * 16 + lhi * 4 + r;
            Ob[row * DH + dt * 16 + llo] = acc[dt][r] / l_run[r];
        }
    }
}

extern "C" void kernel_launch(void* const* d_in, const int* in_sizes, int n_in,
                              void* d_out, int out_size, void* d_ws, size_t ws_size,
                              hipStream_t stream) {
    const float* q = (const float*)d_in[0];
    const float* k = (const float*)d_in[1];
    const float* v = (const float*)d_in[2];
    float* o = (float*)d_out;
    dim3 grid(SEQ / QBLK, 8 * 16);   // 16 q-tiles x 128 batch-heads
    dim3 block(256);
    attn_fwd<<<grid, block, 0, stream>>>(q, k, v, o);
}

// Round 2
// 129.443 us; speedup vs baseline: 1.3843x; 1.3843x over previous
//
#include <hip/hip_runtime.h>
#include <hip/hip_bf16.h>
#include <math.h>

#define SEQ   1024
#define DH    64
#define QBLK  64
#define KBLK  64
#define NBH   128
#define LDK   72   // Ksh/Vsh row stride (shorts): 144B, 16B-aligned
#define LDP   68   // Psh row stride (shorts): 136B -> conflict-free P writes
#define C2    0.1803368801111244f   // 0.125 * log2(e)

typedef short bf16x8 __attribute__((ext_vector_type(8)));
typedef short bf16x4 __attribute__((ext_vector_type(4)));
typedef float f32x4  __attribute__((ext_vector_type(4)));

__device__ inline unsigned short f2bf_rne(float f) {
    union { float f; unsigned u; } x; x.f = f;
    unsigned u = x.u;
    u += 0x7FFFu + ((u >> 16) & 1u);
    return (unsigned short)(u >> 16);
}
__device__ inline unsigned short f2bf_rhu(float f) {   // round-half-up, 2 ops
    union { float f; unsigned u; } x; x.f = f;
    return (unsigned short)((x.u + 0x8000u) >> 16);
}

// ---------------- pre-pass: K -> bf16 row-major, V -> bf16 transposed ----------------
__global__ __launch_bounds__(256)
void conv_kv(const float* __restrict__ K, const float* __restrict__ V,
             unsigned short* __restrict__ Kb, unsigned short* __restrict__ Vt) {
    __shared__ unsigned short T[DH][LDK];
    const int kt  = blockIdx.x;            // 0..15
    const int bh  = blockIdx.y;            // 0..127
    const int tid = threadIdx.x;
    const size_t tile = ((size_t)bh * SEQ + kt * KBLK) * DH;

    // K tile: convert, same layout
    const float* Ks = K + tile;
    unsigned short* Kd = Kb + tile;
    #pragma unroll
    for (int it = 0; it < 4; ++it) {
        const int e = (it * 256 + tid) * 4;
        float4 f = *(const float4*)(Ks + e);
        union { unsigned short s[4]; uint2 u; } p;
        p.s[0] = f2bf_rne(f.x); p.s[1] = f2bf_rne(f.y);
        p.s[2] = f2bf_rne(f.z); p.s[3] = f2bf_rne(f.w);
        *(uint2*)(Kd + e) = p.u;
    }
    // V tile: convert + transpose through LDS
    const float* Vs = V + tile;
    #pragma unroll
    for (int it = 0; it < 4; ++it) {
        const int e = (it * 256 + tid) * 4;
        const int kk = e >> 6, d = e & 63;
        float4 f = *(const float4*)(Vs + e);
        T[d + 0][kk] = f2bf_rne(f.x);
        T[d + 1][kk] = f2bf_rne(f.y);
        T[d + 2][kk] = f2bf_rne(f.z);
        T[d + 3][kk] = f2bf_rne(f.w);
    }
    __syncthreads();
    #pragma unroll
    for (int it = 0; it < 2; ++it) {
        const int e = (it * 256 + tid) * 8;
        const int d = e >> 6, kk0 = e & 63;
        uint4 o = *(const uint4*)&T[d][kk0];
        *(uint4*)(Vt + ((size_t)(bh * DH + d)) * SEQ + kt * KBLK + kk0) = o;
    }
}

// ---------------- main attention kernel ----------------
template<bool PRE>
__global__ __launch_bounds__(256)
void attn_fwd(const float* __restrict__ Q, const float* __restrict__ K,
              const float* __restrict__ V, const unsigned short* __restrict__ Kb,
              const unsigned short* __restrict__ Vt, float* __restrict__ O) {
    __shared__ unsigned short Ksh[KBLK][LDK];      // [kk][d]
    __shared__ unsigned short Vsh[DH][LDK];        // V^T: [d][kk]
    __shared__ unsigned short Psh[4][16][LDP];     // per-wave P tile [q][kk]

    // XCD-chunked swizzle: all 16 q-tiles of one bh land on the same XCD
    const int f  = blockIdx.y * 16 + blockIdx.x;   // grid (16,128) -> flat
    const int w  = (f & 7) * 256 + (f >> 3);       // bijective (2048 % 8 == 0)
    const int qt = w & 15;
    const int bh = w >> 4;

    const int tid  = threadIdx.x;
    const int wave = tid >> 6;
    const int lane = tid & 63;
    const int lhi  = lane >> 4;
    const int llo  = lane & 15;

    const float* Qb = Q + ((size_t)bh * SEQ + qt * QBLK) * DH;
    float*       Ob = O + ((size_t)bh * SEQ + qt * QBLK) * DH;

    // Q fragments (A-operand): rows wave*16+llo, k = s*32 + lhi*8 + j
    bf16x8 qf[2];
    {
        const int qrow = wave * 16 + llo;
        #pragma unroll
        for (int s = 0; s < 2; ++s) {
            const float* p = Qb + qrow * DH + s * 32 + lhi * 8;
            float4 f0 = *(const float4*)(p);
            float4 f1 = *(const float4*)(p + 4);
            qf[s][0] = (short)f2bf_rne(f0.x); qf[s][1] = (short)f2bf_rne(f0.y);
            qf[s][2] = (short)f2bf_rne(f0.z); qf[s][3] = (short)f2bf_rne(f0.w);
            qf[s][4] = (short)f2bf_rne(f1.x); qf[s][5] = (short)f2bf_rne(f1.y);
            qf[s][6] = (short)f2bf_rne(f1.z); qf[s][7] = (short)f2bf_rne(f1.w);
        }
    }

    f32x4 acc[4] = {};
    float m_run[4], l_run[4];
    #pragma unroll
    for (int r = 0; r < 4; ++r) { m_run[r] = -INFINITY; l_run[r] = 0.0f; }

    for (int kt = 0; kt < SEQ / KBLK; ++kt) {
        __syncthreads();
        if (PRE) {
            const unsigned short* Kt = Kb + ((size_t)bh * SEQ + kt * KBLK) * DH;
            #pragma unroll
            for (int it = 0; it < 2; ++it) {
                const int e  = (it * 256 + tid) * 8;
                const int kk = e >> 6, d0 = e & 63;
                uint4 a = *(const uint4*)(Kt + e);
                *(uint4*)&Ksh[kk][d0] = a;
                uint4 b = *(const uint4*)(Vt + (size_t)(bh * DH + kk) * SEQ + kt * KBLK + d0);
                *(uint4*)&Vsh[kk][d0] = b;   // rows = d here (kk var reused as row idx)
            }
        } else {
            const float* Kt = K + ((size_t)bh * SEQ + kt * KBLK) * DH;
            const float* Vs = V + ((size_t)bh * SEQ + kt * KBLK) * DH;
            #pragma unroll
            for (int it = 0; it < 4; ++it) {
                const int e  = (it * 256 + tid) * 4;
                const int kk = e >> 6, d = e & 63;
                float4 kv = *(const float4*)(Kt + e);
                union { unsigned short s[4]; uint2 u; } pk;
                pk.s[0] = f2bf_rne(kv.x); pk.s[1] = f2bf_rne(kv.y);
                pk.s[2] = f2bf_rne(kv.z); pk.s[3] = f2bf_rne(kv.w);
                *(uint2*)&Ksh[kk][d] = pk.u;
                float4 vv = *(const float4*)(Vs + e);
                Vsh[d + 0][kk] = f2bf_rne(vv.x);
                Vsh[d + 1][kk] = f2bf_rne(vv.y);
                Vsh[d + 2][kk] = f2bf_rne(vv.z);
                Vsh[d + 3][kk] = f2bf_rne(vv.w);
            }
        }
        __syncthreads();

        // QK^T (raw scores; scale folded into exp2 arg)
        f32x4 sc[4] = {};
        #pragma unroll
        for (int t = 0; t < 4; ++t) {
            #pragma unroll
            for (int s = 0; s < 2; ++s) {
                bf16x8 b = *(const bf16x8*)&Ksh[t * 16 + llo][s * 32 + lhi * 8];
                sc[t] = __builtin_amdgcn_mfma_f32_16x16x32_bf16(qf[s], b, sc[t], 0, 0, 0);
            }
        }

        // online softmax on raw scores
        float corr[4], mC[4];
        #pragma unroll
        for (int r = 0; r < 4; ++r) {
            float v = fmaxf(fmaxf(sc[0][r], sc[1][r]), fmaxf(sc[2][r], sc[3][r]));
            v = fmaxf(v, __shfl_xor(v, 1));
            v = fmaxf(v, __shfl_xor(v, 2));
            v = fmaxf(v, __shfl_xor(v, 4));
            v = fmaxf(v, __shfl_xor(v, 8));
            float mn = fmaxf(m_run[r], v);
            corr[r] = __builtin_amdgcn_exp2f((m_run[r] - mn) * C2);
            m_run[r] = mn;
            mC[r] = mn * C2;
        }
        float rsum[4] = {0.f, 0.f, 0.f, 0.f};
        #pragma unroll
        for (int t = 0; t < 4; ++t) {
            #pragma unroll
            for (int r = 0; r < 4; ++r) {
                float p = __builtin_amdgcn_exp2f(__builtin_fmaf(sc[t][r], C2, -mC[r]));
                rsum[r] += p;
                Psh[wave][lhi * 4 + r][t * 16 + llo] = f2bf_rhu(p);
            }
        }
        #pragma unroll
        for (int r = 0; r < 4; ++r) {
            float v = rsum[r];
            v += __shfl_xor(v, 1);
            v += __shfl_xor(v, 2);
            v += __shfl_xor(v, 4);
            v += __shfl_xor(v, 8);
            l_run[r] = l_run[r] * corr[r] + v;
        }
        #pragma unroll
        for (int dt = 0; dt < 4; ++dt)
            #pragma unroll
            for (int r = 0; r < 4; ++r) acc[dt][r] *= corr[r];

        // PV
        #pragma unroll
        for (int s2 = 0; s2 < 2; ++s2) {
            bf16x4 pa0 = *(const bf16x4*)&Psh[wave][llo][s2 * 32 + lhi * 8];
            bf16x4 pa1 = *(const bf16x4*)&Psh[wave][llo][s2 * 32 + lhi * 8 + 4];
            bf16x8 a = {pa0[0], pa0[1], pa0[2], pa0[3], pa1[0], pa1[1], pa1[2], pa1[3]};
            #pragma unroll
            for (int dt = 0; dt < 4; ++dt) {
                bf16x8 b = *(const bf16x8*)&Vsh[dt * 16 + llo][s2 * 32 + lhi * 8];
                acc[dt] = __builtin_amdgcn_mfma_f32_16x16x32_bf16(a, b, acc[dt], 0, 0, 0);
            }
        }
    }

    #pragma unroll
    for (int r = 0; r < 4; ++r) {
        const float inv = 1.0f / l_run[r];
        const int row = wave * 16 + lhi * 4 + r;
        #pragma unroll
        for (int dt = 0; dt < 4; ++dt)
            Ob[row * DH + dt * 16 + llo] = acc[dt][r] * inv;
    }
}

extern "C" void kernel_launch(void* const* d_in, const int* in_sizes, int n_in,
                              void* d_out, int out_size, void* d_ws, size_t ws_size,
                              hipStream_t stream) {
    const float* q = (const float*)d_in[0];
    const float* k = (const float*)d_in[1];
    const float* v = (const float*)d_in[2];
    float* o = (float*)d_out;

    const size_t nkv = (size_t)NBH * SEQ * DH;           // 8.39M elems
    dim3 grid(SEQ / QBLK, NBH), block(256);

    if (ws_size >= 2 * nkv * sizeof(unsigned short)) {
        unsigned short* Kb = (unsigned short*)d_ws;
        unsigned short* Vt = Kb + nkv;
        conv_kv<<<grid, block, 0, stream>>>(k, v, Kb, Vt);
        attn_fwd<true><<<grid, block, 0, stream>>>(q, k, v, Kb, Vt, o);
    } else {
        attn_fwd<false><<<grid, block, 0, stream>>>(q, k, v, nullptr, nullptr, o);
    }
}

// Round 3
// 95.612 us; speedup vs baseline: 1.8741x; 1.3538x over previous
//
#include <hip/hip_runtime.h>
#include <hip/hip_bf16.h>
#include <math.h>

#define SEQ   1024
#define DH    64
#define QBLK  64
#define KBLK  64
#define NBH   128
#define LDK   72   // Ksh/Vsh row stride (shorts): 144B -> 8-way b128 reads = LDS BW floor
#define LDP   72   // Psh row stride
#define C2    0.1803368801111244f   // 0.125 * log2(e)
#define DEFER_THR 44.0f             // raw-score defer threshold (~8 in exp2 domain)

typedef short bf16x8 __attribute__((ext_vector_type(8)));
typedef float f32x4  __attribute__((ext_vector_type(4)));

__device__ inline unsigned short f2bf_rne(float f) {
    union { float f; unsigned u; } x; x.f = f;
    unsigned u = x.u;
    u += 0x7FFFu + ((u >> 16) & 1u);
    return (unsigned short)(u >> 16);
}
// pack two floats -> two bf16 (round-half-up) in one u32: 2 adds + v_perm
__device__ inline unsigned pack_bf16(float lo, float hi) {
    union { float f; unsigned u; } a, b; a.f = lo; b.f = hi;
    return __builtin_amdgcn_perm(b.u + 0x8000u, a.u + 0x8000u, 0x07060302u);
}

// ---------------- pre-pass: K -> bf16 row-major, V -> bf16 transposed ----------------
__global__ __launch_bounds__(256)
void conv_kv(const float* __restrict__ K, const float* __restrict__ V,
             unsigned short* __restrict__ Kb, unsigned short* __restrict__ Vt) {
    __shared__ unsigned short T[DH][LDK];
    const int kt  = blockIdx.x;
    const int bh  = blockIdx.y;
    const int tid = threadIdx.x;
    const size_t tile = ((size_t)bh * SEQ + kt * KBLK) * DH;

    const float* Ks = K + tile;
    unsigned short* Kd = Kb + tile;
    #pragma unroll
    for (int it = 0; it < 4; ++it) {
        const int e = (it * 256 + tid) * 4;
        float4 f = *(const float4*)(Ks + e);
        union { unsigned short s[4]; uint2 u; } p;
        p.s[0] = f2bf_rne(f.x); p.s[1] = f2bf_rne(f.y);
        p.s[2] = f2bf_rne(f.z); p.s[3] = f2bf_rne(f.w);
        *(uint2*)(Kd + e) = p.u;
    }
    const float* Vs = V + tile;
    #pragma unroll
    for (int it = 0; it < 4; ++it) {
        const int e = (it * 256 + tid) * 4;
        const int kk = e >> 6, d = e & 63;
        float4 f = *(const float4*)(Vs + e);
        T[d + 0][kk] = f2bf_rne(f.x);
        T[d + 1][kk] = f2bf_rne(f.y);
        T[d + 2][kk] = f2bf_rne(f.z);
        T[d + 3][kk] = f2bf_rne(f.w);
    }
    __syncthreads();
    #pragma unroll
    for (int it = 0; it < 2; ++it) {
        const int e = (it * 256 + tid) * 8;
        const int d = e >> 6, kk0 = e & 63;
        uint4 o = *(const uint4*)&T[d][kk0];
        *(uint4*)(Vt + ((size_t)(bh * DH + d)) * SEQ + kt * KBLK + kk0) = o;
    }
}

// ---------------- main attention kernel (swapped QK^T) ----------------
template<bool PRE>
__global__ __launch_bounds__(256)
void attn_fwd(const float* __restrict__ Q, const float* __restrict__ K,
              const float* __restrict__ V, const unsigned short* __restrict__ Kb,
              const unsigned short* __restrict__ Vt, float* __restrict__ O) {
    __shared__ unsigned short Ksh[KBLK][LDK];      // [kk][d]
    __shared__ unsigned short Vsh[DH][LDK];        // V^T: [d][kk]
    __shared__ unsigned short Psh[4][16][LDP];     // per-wave P tile [q][kk]

    // XCD-chunked swizzle: all 16 q-tiles of one bh land on the same XCD
    const int f  = blockIdx.y * 16 + blockIdx.x;
    const int w  = (f & 7) * 256 + (f >> 3);       // bijective (2048 % 8 == 0)
    const int qt = w & 15;
    const int bh = w >> 4;

    const int tid  = threadIdx.x;
    const int wave = tid >> 6;
    const int lane = tid & 63;
    const int lhi  = lane >> 4;     // 0..3
    const int llo  = lane & 15;     // 0..15  == this lane's q-row (softmax state)
    const int base = lane & 48;     // lhi*16, for intra-16-group broadcasts

    const float* Qb = Q + ((size_t)bh * SEQ + qt * QBLK) * DH;
    float*       Ob = O + ((size_t)bh * SEQ + qt * QBLK) * DH;

    // Q fragments (B-operand of swapped QK^T): col=llo=q, k = s*32 + lhi*8 + j
    bf16x8 qf[2];
    {
        const int qrow = wave * 16 + llo;
        #pragma unroll
        for (int s = 0; s < 2; ++s) {
            const float* p = Qb + qrow * DH + s * 32 + lhi * 8;
            float4 f0 = *(const float4*)(p);
            float4 f1 = *(const float4*)(p + 4);
            qf[s][0] = (short)f2bf_rne(f0.x); qf[s][1] = (short)f2bf_rne(f0.y);
            qf[s][2] = (short)f2bf_rne(f0.z); qf[s][3] = (short)f2bf_rne(f0.w);
            qf[s][4] = (short)f2bf_rne(f1.x); qf[s][5] = (short)f2bf_rne(f1.y);
            qf[s][6] = (short)f2bf_rne(f1.z); qf[s][7] = (short)f2bf_rne(f1.w);
        }
    }

    f32x4 acc[4] = {};              // O tile: col=llo=d_local, row=lhi*4+r=q_local
    float m_run = -INFINITY;        // softmax state for q = wave*16 + llo
    float l_run = 0.0f;

    for (int kt = 0; kt < SEQ / KBLK; ++kt) {
        __syncthreads();
        if (PRE) {
            const unsigned short* Kt = Kb + ((size_t)bh * SEQ + kt * KBLK) * DH;
            #pragma unroll
            for (int it = 0; it < 2; ++it) {
                const int e  = (it * 256 + tid) * 8;
                const int kk = e >> 6, d0 = e & 63;
                uint4 a = *(const uint4*)(Kt + e);
                *(uint4*)&Ksh[kk][d0] = a;
                uint4 b = *(const uint4*)(Vt + (size_t)(bh * DH + kk) * SEQ + kt * KBLK + d0);
                *(uint4*)&Vsh[kk][d0] = b;
            }
        } else {
            const float* Kt = K + ((size_t)bh * SEQ + kt * KBLK) * DH;
            const float* Vs = V + ((size_t)bh * SEQ + kt * KBLK) * DH;
            #pragma unroll
            for (int it = 0; it < 4; ++it) {
                const int e  = (it * 256 + tid) * 4;
                const int kk = e >> 6, d = e & 63;
                float4 kv = *(const float4*)(Kt + e);
                union { unsigned short s[4]; uint2 u; } pk;
                pk.s[0] = f2bf_rne(kv.x); pk.s[1] = f2bf_rne(kv.y);
                pk.s[2] = f2bf_rne(kv.z); pk.s[3] = f2bf_rne(kv.w);
                *(uint2*)&Ksh[kk][d] = pk.u;
                float4 vv = *(const float4*)(Vs + e);
                Vsh[d + 0][kk] = f2bf_rne(vv.x);
                Vsh[d + 1][kk] = f2bf_rne(vv.y);
                Vsh[d + 2][kk] = f2bf_rne(vv.z);
                Vsh[d + 3][kk] = f2bf_rne(vv.w);
            }
        }
        __syncthreads();

        // ---- swapped QK^T: st[t][r] = S[q=llo][kk = t*16 + lhi*4 + r] ----
        f32x4 st[4] = {};
        #pragma unroll
        for (int t = 0; t < 4; ++t) {
            #pragma unroll
            for (int s = 0; s < 2; ++s) {
                bf16x8 kf = *(const bf16x8*)&Ksh[t * 16 + llo][s * 32 + lhi * 8];
                st[t] = __builtin_amdgcn_mfma_f32_16x16x32_bf16(kf, qf[s], st[t], 0, 0, 0);
            }
        }

        // ---- tile max (in-lane 16 + cross lhi-groups) ----
        float tmax = st[0][0];
        #pragma unroll
        for (int t = 0; t < 4; ++t)
            #pragma unroll
            for (int r = 0; r < 4; ++r) tmax = fmaxf(tmax, st[t][r]);
        tmax = fmaxf(tmax, __shfl_xor(tmax, 16));
        tmax = fmaxf(tmax, __shfl_xor(tmax, 32));

        // ---- defer-max: rescale only when some row's max grew past THR ----
        if (__any(tmax > m_run + DEFER_THR)) {
            float mn   = fmaxf(m_run, tmax);
            float corr = exp2f((m_run - mn) * C2);   // first tile: exp2(-inf)=0
            m_run = mn;
            l_run *= corr;
            #pragma unroll
            for (int r = 0; r < 4; ++r) {
                float cr = __shfl(corr, base | (lhi * 4 + r));
                #pragma unroll
                for (int dt = 0; dt < 4; ++dt) acc[dt][r] *= cr;
            }
        }

        // ---- P = exp2((S - m)*C2); pack to bf16; vectorized LDS write ----
        const float mC = m_run * C2;
        float tsum = 0.0f;
        #pragma unroll
        for (int t = 0; t < 4; ++t) {
            float p0 = exp2f(__builtin_fmaf(st[t][0], C2, -mC));
            float p1 = exp2f(__builtin_fmaf(st[t][1], C2, -mC));
            float p2 = exp2f(__builtin_fmaf(st[t][2], C2, -mC));
            float p3 = exp2f(__builtin_fmaf(st[t][3], C2, -mC));
            tsum += (p0 + p1) + (p2 + p3);
            uint2 pk;
            pk.x = pack_bf16(p0, p1);
            pk.y = pack_bf16(p2, p3);
            *(uint2*)&Psh[wave][llo][t * 16 + lhi * 4] = pk;
        }
        tsum += __shfl_xor(tsum, 16);
        tsum += __shfl_xor(tsum, 32);
        l_run += tsum;

        // ---- PV: acc[q][d] += P[q][kk] V[kk][d] ----
        #pragma unroll
        for (int s2 = 0; s2 < 2; ++s2) {
            bf16x8 pa = *(const bf16x8*)&Psh[wave][llo][s2 * 32 + lhi * 8];
            #pragma unroll
            for (int dt = 0; dt < 4; ++dt) {
                bf16x8 vf = *(const bf16x8*)&Vsh[dt * 16 + llo][s2 * 32 + lhi * 8];
                acc[dt] = __builtin_amdgcn_mfma_f32_16x16x32_bf16(pa, vf, acc[dt], 0, 0, 0);
            }
        }
    }

    // ---- epilogue: broadcast 1/l to C-layout rows, coalesced store ----
    const float linv = 1.0f / l_run;
    #pragma unroll
    for (int r = 0; r < 4; ++r) {
        const float lr = __shfl(linv, base | (lhi * 4 + r));
        const int row = wave * 16 + lhi * 4 + r;
        #pragma unroll
        for (int dt = 0; dt < 4; ++dt)
            Ob[row * DH + dt * 16 + llo] = acc[dt][r] * lr;
    }
}

extern "C" void kernel_launch(void* const* d_in, const int* in_sizes, int n_in,
                              void* d_out, int out_size, void* d_ws, size_t ws_size,
                              hipStream_t stream) {
    const float* q = (const float*)d_in[0];
    const float* k = (const float*)d_in[1];
    const float* v = (const float*)d_in[2];
    float* o = (float*)d_out;

    const size_t nkv = (size_t)NBH * SEQ * DH;
    dim3 grid(SEQ / QBLK, NBH), block(256);

    if (ws_size >= 2 * nkv * sizeof(unsigned short)) {
        unsigned short* Kb = (unsigned short*)d_ws;
        unsigned short* Vt = Kb + nkv;
        conv_kv<<<grid, block, 0, stream>>>(k, v, Kb, Vt);
        attn_fwd<true><<<grid, block, 0, stream>>>(q, k, v, Kb, Vt, o);
    } else {
        attn_fwd<false><<<grid, block, 0, stream>>>(q, k, v, nullptr, nullptr, o);
    }
}